// Round 3
// baseline (194.218 us; speedup 1.0000x reference)
//
#include <hip/hip_runtime.h>
#include <hip/hip_bf16.h>

#define LN_EPS 1e-5f

// Kernel 1: hi'[row,e] = sum_k x[row,k]*W1[k,e] + b1[e]   (b1 folded into hi)
//           hj [row,e] = sum_k x[row,k]*W1[256+k,e]
// 8 rows/block, 256 threads: t<128 -> hi half (2 cols each), t>=128 -> hj half.
__global__ __launch_bounds__(256) void k_gemm_hij(
    const float* __restrict__ x,    // [2048,256] f32
    const float* __restrict__ W1,   // [512,256] f32
    const float* __restrict__ b1,   // [256] f32
    float* __restrict__ hi_ws,      // [2048,256] f32
    float* __restrict__ hj_ws)      // [2048,256] f32
{
    __shared__ float xs[8][256];
    const int t = threadIdx.x;
    const int row0 = blockIdx.x * 8;

    // stage 8 rows of x into LDS (8 consecutive floats per thread)
    {
        const float4* xv = (const float4*)(x + (size_t)row0 * 256);
        float4 a = xv[t * 2], b = xv[t * 2 + 1];
        float* xrow = &xs[t >> 5][(t * 8) & 255];
        xrow[0] = a.x; xrow[1] = a.y; xrow[2] = a.z; xrow[3] = a.w;
        xrow[4] = b.x; xrow[5] = b.y; xrow[6] = b.z; xrow[7] = b.w;
    }
    __syncthreads();

    const int half = t >> 7;       // 0 = hi, 1 = hj
    const int e2 = (t & 127) * 2;  // this thread's two output columns
    const float* Wb = W1 + (size_t)half * 65536 + e2;

    float acc0[8], acc1[8];
#pragma unroll
    for (int r = 0; r < 8; r++) { acc0[r] = 0.f; acc1[r] = 0.f; }

    for (int k = 0; k < 256; k++) {
        float2 wv = *(const float2*)(Wb + (size_t)k * 256);
#pragma unroll
        for (int r = 0; r < 8; r++) {
            float xr = xs[r][k];
            acc0[r] = fmaf(xr, wv.x, acc0[r]);
            acc1[r] = fmaf(xr, wv.y, acc1[r]);
        }
    }

    float add0 = 0.f, add1 = 0.f;
    if (half == 0) { add0 = b1[e2]; add1 = b1[e2 + 1]; }
    float* dst = half ? hj_ws : hi_ws;
#pragma unroll
    for (int r = 0; r < 8; r++) {
        *(float2*)&dst[(size_t)(row0 + r) * 256 + e2] =
            make_float2(acc0[r] + add0, acc1[r] + add1);
    }
}

// Kernel 2: one block per (b,n). scores -> softmax -> ctx -> proj -> LN -> +x.
__global__ __launch_bounds__(256) void k_fused(
    const float* __restrict__ x,      // [8,256,256] f32
    const float* __restrict__ hi_ws,  // [2048,256] f32 (b1 folded)
    const float* __restrict__ hj_ws,  // [2048,256] f32
    const float* __restrict__ W2,     // [256] f32
    const float* __restrict__ b2,     // [1] f32
    const float* __restrict__ Wp,     // [256,256] f32
    const float* __restrict__ bp,     // [256] f32
    const float* __restrict__ gma,    // [256] f32
    const float* __restrict__ bta,    // [256] f32
    float* __restrict__ out)          // [8,256,256] f32
{
    const int t = threadIdx.x;
    const int bn = blockIdx.x;
    const int b = bn >> 8;
    const int n = bn & 255;

    __shared__ float hi_s[256];
    __shared__ float w2_s[256];
    __shared__ float red[256];
    __shared__ float wt_s[256];
    __shared__ float ctx_s[256];

    hi_s[t] = hi_ws[(size_t)bn * 256 + t];
    w2_s[t] = W2[t];
    __syncthreads();

    // ---- phase 1: score for m = t ----
    const float* hjr = hj_ws + (size_t)(b * 256 + t) * 256;
    float acc = 0.f;
    for (int d = 0; d < 256; d += 4) {
        float4 h4 = *(const float4*)(hjr + d);
        acc = fmaf(fmaxf(hi_s[d]     + h4.x, 0.f), w2_s[d],     acc);
        acc = fmaf(fmaxf(hi_s[d + 1] + h4.y, 0.f), w2_s[d + 1], acc);
        acc = fmaf(fmaxf(hi_s[d + 2] + h4.z, 0.f), w2_s[d + 2], acc);
        acc = fmaf(fmaxf(hi_s[d + 3] + h4.w, 0.f), w2_s[d + 3], acc);
    }
    float s = acc + b2[0];
    if (t == n) s = 0.f;  // reference leaves diagonal exactly 0

    // ---- softmax over 256 values ----
    red[t] = s;
    __syncthreads();
    for (int off = 128; off > 0; off >>= 1) {
        if (t < off) red[t] = fmaxf(red[t], red[t + off]);
        __syncthreads();
    }
    float mx = red[0];
    __syncthreads();
    float ev = __expf(s - mx);
    red[t] = ev;
    __syncthreads();
    for (int off = 128; off > 0; off >>= 1) {
        if (t < off) red[t] += red[t + off];
        __syncthreads();
    }
    float inv = 1.f / red[0];
    wt_s[t] = ev * inv;
    __syncthreads();

    // ---- phase 2: ctx for d = t ----
    const float* xb = x + (size_t)b * 65536 + t;
    float c = 0.f;
    for (int m = 0; m < 256; m++) c = fmaf(wt_s[m], xb[(size_t)m * 256], c);
    ctx_s[t] = c;
    __syncthreads();

    // ---- phase 3: proj for e = t ----
    float p = bp[t];
    const float* W = Wp + t;
    for (int d = 0; d < 256; d++) p = fmaf(ctx_s[d], W[(size_t)d * 256], p);

    // ---- phase 4: LayerNorm + residual ----
    red[t] = p;
    __syncthreads();
    for (int off = 128; off > 0; off >>= 1) {
        if (t < off) red[t] += red[t + off];
        __syncthreads();
    }
    float mu = red[0] * (1.f / 256.f);
    __syncthreads();
    float dv = p - mu;
    red[t] = dv * dv;
    __syncthreads();
    for (int off = 128; off > 0; off >>= 1) {
        if (t < off) red[t] += red[t + off];
        __syncthreads();
    }
    float var = red[0] * (1.f / 256.f);
    float ln = dv * rsqrtf(var + LN_EPS) * gma[t] + bta[t];
    out[(size_t)bn * 256 + t] = x[(size_t)bn * 256 + t] + ln;
}

extern "C" void kernel_launch(void* const* d_in, const int* in_sizes, int n_in,
                              void* d_out, int out_size, void* d_ws, size_t ws_size,
                              hipStream_t stream) {
    const float* x   = (const float*)d_in[0];
    const float* W1  = (const float*)d_in[1];
    const float* b1  = (const float*)d_in[2];
    const float* W2  = (const float*)d_in[3];
    const float* b2  = (const float*)d_in[4];
    const float* Wp  = (const float*)d_in[5];
    const float* bp  = (const float*)d_in[6];
    const float* gma = (const float*)d_in[7];
    const float* bta = (const float*)d_in[8];
    float* out = (float*)d_out;

    float* hi_ws = (float*)d_ws;                  // [2048,256] f32, 2 MB
    float* hj_ws = hi_ws + (size_t)2048 * 256;    // [2048,256] f32, 2 MB

    k_gemm_hij<<<256, 256, 0, stream>>>(x, W1, b1, hi_ws, hj_ws);
    k_fused<<<2048, 256, 0, stream>>>(x, hi_ws, hj_ws, W2, b2, Wp, bp,
                                      gma, bta, out);
}

// Round 4
// 130.461 us; speedup vs baseline: 1.4887x; 1.4887x over previous
//
#include <hip/hip_runtime.h>

#define LN_EPS 1e-5f

__device__ __forceinline__ float wred_max(float v) {
#pragma unroll
    for (int off = 32; off; off >>= 1) v = fmaxf(v, __shfl_xor(v, off, 64));
    return v;
}
__device__ __forceinline__ float wred_sum(float v) {
#pragma unroll
    for (int off = 32; off; off >>= 1) v += __shfl_xor(v, off, 64);
    return v;
}

// Kernel 1: hi_ws[row][e] = x[row]·W1[:256][e] + b1[e]
//           hjT[b][e][m]  = x[b*256+m]·W1[256:][e]      (transposed store!)
// 4 rows/block, 512 blocks. t<128 -> hi half (2 cols), t>=128 -> hj half.
__global__ __launch_bounds__(256) void k_gemm_hij(
    const float* __restrict__ x,    // [2048,256]
    const float* __restrict__ W1,   // [512,256]
    const float* __restrict__ b1,   // [256]
    float* __restrict__ hi_ws,      // [2048,256]
    float* __restrict__ hjT)        // [8,256,256]  (b, e, m)
{
    __shared__ __align__(16) float xs[4][256];
    const int t = threadIdx.x;
    const int row0 = blockIdx.x * 4;

    ((float4*)&xs[0][0])[t] = ((const float4*)(x + (size_t)row0 * 256))[t];
    __syncthreads();

    const int half = t >> 7;
    const int e2 = (t & 127) * 2;
    const float* Wb = W1 + (size_t)half * 65536 + e2;

    float a0[4], a1[4];
#pragma unroll
    for (int r = 0; r < 4; r++) { a0[r] = 0.f; a1[r] = 0.f; }

    for (int k = 0; k < 256; k += 4) {
        float2 w0 = *(const float2*)(Wb + (size_t)(k + 0) * 256);
        float2 w1 = *(const float2*)(Wb + (size_t)(k + 1) * 256);
        float2 w2 = *(const float2*)(Wb + (size_t)(k + 2) * 256);
        float2 w3 = *(const float2*)(Wb + (size_t)(k + 3) * 256);
#pragma unroll
        for (int r = 0; r < 4; r++) {
            float4 xr = *(const float4*)&xs[r][k];
            a0[r] = fmaf(xr.x, w0.x, a0[r]); a1[r] = fmaf(xr.x, w0.y, a1[r]);
            a0[r] = fmaf(xr.y, w1.x, a0[r]); a1[r] = fmaf(xr.y, w1.y, a1[r]);
            a0[r] = fmaf(xr.z, w2.x, a0[r]); a1[r] = fmaf(xr.z, w2.y, a1[r]);
            a0[r] = fmaf(xr.w, w3.x, a0[r]); a1[r] = fmaf(xr.w, w3.y, a1[r]);
        }
    }

    if (half == 0) {
        float add0 = b1[e2], add1 = b1[e2 + 1];
#pragma unroll
        for (int r = 0; r < 4; r++)
            *(float2*)&hi_ws[(size_t)(row0 + r) * 256 + e2] =
                make_float2(a0[r] + add0, a1[r] + add1);
    } else {
        const int b = row0 >> 8, mloc = row0 & 255;
        *(float4*)&hjT[((size_t)(b * 256 + e2)) * 256 + mloc] =
            make_float4(a0[0], a0[1], a0[2], a0[3]);
        *(float4*)&hjT[((size_t)(b * 256 + e2 + 1)) * 256 + mloc] =
            make_float4(a1[0], a1[1], a1[2], a1[3]);
    }
}

// Kernel 2: 4 n's per block (same b), 512 blocks.
// scores -> softmax -> ctx -> proj -> LN -> +x, all coalesced + unrolled.
__global__ __launch_bounds__(256) void k_fused(
    const float* __restrict__ x,      // [8,256,256]
    const float* __restrict__ hi_ws,  // [2048,256] (b1 folded)
    const float* __restrict__ hjT,    // [8,256,256] (b, d, m)
    const float* __restrict__ W2, const float* __restrict__ b2,
    const float* __restrict__ Wp, const float* __restrict__ bp,
    const float* __restrict__ gma, const float* __restrict__ bta,
    float* __restrict__ out)
{
    const int t = threadIdx.x;
    const int lane = t & 63, wv = t >> 6;
    const int bn0 = blockIdx.x * 4;
    const int b = bn0 >> 8, n0 = bn0 & 255;

    __shared__ __align__(16) float hi_s[4][256];
    __shared__ __align__(16) float w2_s[256];
    __shared__ __align__(16) float wt_s[4][256];
    __shared__ __align__(16) float ctx_s[4][256];
    __shared__ float part[8][4];

#pragma unroll
    for (int i = 0; i < 4; i++) hi_s[i][t] = hi_ws[(size_t)(bn0 + i) * 256 + t];
    w2_s[t] = W2[t];
    __syncthreads();

    // ---- phase 1: scores; thread t = column m, 4 rows n0..n0+3 ----
    const float* hjb = hjT + (size_t)b * 65536 + t;   // + d*256, coalesced in t
    float s[4] = {0.f, 0.f, 0.f, 0.f};
    for (int d = 0; d < 256; d += 4) {
        float h0 = hjb[(size_t)(d + 0) * 256];
        float h1 = hjb[(size_t)(d + 1) * 256];
        float h2 = hjb[(size_t)(d + 2) * 256];
        float h3 = hjb[(size_t)(d + 3) * 256];
        float4 w4 = *(const float4*)&w2_s[d];
#pragma unroll
        for (int i = 0; i < 4; i++) {
            float4 hi4 = *(const float4*)&hi_s[i][d];
            s[i] = fmaf(fmaxf(hi4.x + h0, 0.f), w4.x, s[i]);
            s[i] = fmaf(fmaxf(hi4.y + h1, 0.f), w4.y, s[i]);
            s[i] = fmaf(fmaxf(hi4.z + h2, 0.f), w4.z, s[i]);
            s[i] = fmaf(fmaxf(hi4.w + h3, 0.f), w4.w, s[i]);
        }
    }
    float b2v = b2[0];
#pragma unroll
    for (int i = 0; i < 4; i++) {
        s[i] += b2v;
        if (t == n0 + i) s[i] = 0.f;   // reference leaves diagonal exactly 0
    }

    // ---- softmax (shuffle reductions, 2 barriers) ----
#pragma unroll
    for (int i = 0; i < 4; i++) {
        float m = wred_max(s[i]);
        if (lane == 0) part[i][wv] = m;
    }
    __syncthreads();
    float ev[4];
#pragma unroll
    for (int i = 0; i < 4; i++) {
        float mx = fmaxf(fmaxf(part[i][0], part[i][1]),
                         fmaxf(part[i][2], part[i][3]));
        ev[i] = __expf(s[i] - mx);
        float sm = wred_sum(ev[i]);
        if (lane == 0) part[4 + i][wv] = sm;
    }
    __syncthreads();
#pragma unroll
    for (int i = 0; i < 4; i++) {
        float tot = (part[4 + i][0] + part[4 + i][1]) +
                    (part[4 + i][2] + part[4 + i][3]);
        wt_s[i][t] = ev[i] / tot;
    }
    __syncthreads();

    // ---- phase 2: ctx; thread t = d ----
    const float* xb = x + (size_t)b * 65536 + t;
    float c[4] = {0.f, 0.f, 0.f, 0.f};
    for (int m = 0; m < 256; m += 4) {
        float x0 = xb[(size_t)(m + 0) * 256];
        float x1 = xb[(size_t)(m + 1) * 256];
        float x2 = xb[(size_t)(m + 2) * 256];
        float x3 = xb[(size_t)(m + 3) * 256];
#pragma unroll
        for (int i = 0; i < 4; i++) {
            float4 w4 = *(const float4*)&wt_s[i][m];
            c[i] = fmaf(w4.x, x0, c[i]);
            c[i] = fmaf(w4.y, x1, c[i]);
            c[i] = fmaf(w4.z, x2, c[i]);
            c[i] = fmaf(w4.w, x3, c[i]);
        }
    }
#pragma unroll
    for (int i = 0; i < 4; i++) ctx_s[i][t] = c[i];
    __syncthreads();

    // ---- phase 3: proj; thread t = e ----
    float bpv = bp[t];
    float p[4] = {bpv, bpv, bpv, bpv};
    const float* Wc = Wp + t;
    for (int d = 0; d < 256; d += 4) {
        float q0 = Wc[(size_t)(d + 0) * 256];
        float q1 = Wc[(size_t)(d + 1) * 256];
        float q2 = Wc[(size_t)(d + 2) * 256];
        float q3 = Wc[(size_t)(d + 3) * 256];
#pragma unroll
        for (int i = 0; i < 4; i++) {
            float4 c4 = *(const float4*)&ctx_s[i][d];
            p[i] = fmaf(c4.x, q0, p[i]);
            p[i] = fmaf(c4.y, q1, p[i]);
            p[i] = fmaf(c4.z, q2, p[i]);
            p[i] = fmaf(c4.w, q3, p[i]);
        }
    }

    // ---- phase 4: LayerNorm (one shuffle round for sum+sumsq) + residual ----
#pragma unroll
    for (int i = 0; i < 4; i++) {
        float su = wred_sum(p[i]);
        float sq = wred_sum(p[i] * p[i]);
        if (lane == 0) { part[i][wv] = su; part[4 + i][wv] = sq; }
    }
    __syncthreads();
    float gv = gma[t], bv = bta[t];
#pragma unroll
    for (int i = 0; i < 4; i++) {
        float su = (part[i][0] + part[i][1]) + (part[i][2] + part[i][3]);
        float sq = (part[4 + i][0] + part[4 + i][1]) +
                   (part[4 + i][2] + part[4 + i][3]);
        float mu = su * (1.f / 256.f);
        float var = sq * (1.f / 256.f) - mu * mu;
        float ln = (p[i] - mu) * rsqrtf(var + LN_EPS) * gv + bv;
        out[(size_t)(bn0 + i) * 256 + t] = x[(size_t)(bn0 + i) * 256 + t] + ln;
    }
}

extern "C" void kernel_launch(void* const* d_in, const int* in_sizes, int n_in,
                              void* d_out, int out_size, void* d_ws, size_t ws_size,
                              hipStream_t stream) {
    const float* x   = (const float*)d_in[0];
    const float* W1  = (const float*)d_in[1];
    const float* b1  = (const float*)d_in[2];
    const float* W2  = (const float*)d_in[3];
    const float* b2  = (const float*)d_in[4];
    const float* Wp  = (const float*)d_in[5];
    const float* bp  = (const float*)d_in[6];
    const float* gma = (const float*)d_in[7];
    const float* bta = (const float*)d_in[8];
    float* out = (float*)d_out;

    float* hi_ws = (float*)d_ws;                  // [2048,256] f32, 2 MB
    float* hjT   = hi_ws + (size_t)2048 * 256;    // [8,256,256] f32, 2 MB

    k_gemm_hij<<<512, 256, 0, stream>>>(x, W1, b1, hi_ws, hjT);
    k_fused<<<512, 256, 0, stream>>>(x, hi_ws, hjT, W2, b2, Wp, bp,
                                     gma, bta, out);
}

// Round 5
// 113.433 us; speedup vs baseline: 1.7122x; 1.1501x over previous
//
#include <hip/hip_runtime.h>

#define LN_EPS 1e-5f

__device__ __forceinline__ float wred_max(float v) {
#pragma unroll
    for (int off = 32; off; off >>= 1) v = fmaxf(v, __shfl_xor(v, off, 64));
    return v;
}
__device__ __forceinline__ float wred_sum(float v) {
#pragma unroll
    for (int off = 32; off; off >>= 1) v += __shfl_xor(v, off, 64);
    return v;
}

// Kernel 1: hi_ws[row][e] = x[row]·W1[:256][e] + b1[e]
//           hjT[b][e][m]  = x[b*256+m]·W1[256:][e]   (transposed store)
// 512 blocks × 256 thr, 4 rows/block. Wave w: half=w>>1 (0 hi, 1 hj),
// rows r0=(w&1)*2 .. +1. Lane owns 4 output columns e=4*lane..+3 (float4
// loads of W1 rows -> coalesced 1KB/wave-instr).
__global__ __launch_bounds__(256) void k_gemm_hij(
    const float* __restrict__ x,    // [2048,256]
    const float* __restrict__ W1,   // [512,256]
    const float* __restrict__ b1,   // [256]
    float* __restrict__ hi_ws,      // [2048,256]
    float* __restrict__ hjT)        // [8,256,256] (b, e, m)
{
    __shared__ __align__(16) float xs[4][256];
    const int t = threadIdx.x;
    const int lane = t & 63, w = t >> 6;
    const int row0 = blockIdx.x * 4;

    ((float4*)xs)[t] = ((const float4*)(x + (size_t)row0 * 256))[t];
    __syncthreads();

    const int half = w >> 1;
    const int r0 = (w & 1) * 2;
    const float* Wb = W1 + (size_t)half * 65536 + 4 * lane;

    float a00 = 0.f, a01 = 0.f, a02 = 0.f, a03 = 0.f;
    float a10 = 0.f, a11 = 0.f, a12 = 0.f, a13 = 0.f;

#pragma unroll 2
    for (int k = 0; k < 256; k += 4) {
        float4 q0 = *(const float4*)(Wb + (size_t)(k + 0) * 256);
        float4 q1 = *(const float4*)(Wb + (size_t)(k + 1) * 256);
        float4 q2 = *(const float4*)(Wb + (size_t)(k + 2) * 256);
        float4 q3 = *(const float4*)(Wb + (size_t)(k + 3) * 256);
        float4 xa = *(const float4*)&xs[r0][k];
        float4 xb = *(const float4*)&xs[r0 + 1][k];
        a00 = fmaf(xa.x, q0.x, a00); a00 = fmaf(xa.y, q1.x, a00);
        a00 = fmaf(xa.z, q2.x, a00); a00 = fmaf(xa.w, q3.x, a00);
        a01 = fmaf(xa.x, q0.y, a01); a01 = fmaf(xa.y, q1.y, a01);
        a01 = fmaf(xa.z, q2.y, a01); a01 = fmaf(xa.w, q3.y, a01);
        a02 = fmaf(xa.x, q0.z, a02); a02 = fmaf(xa.y, q1.z, a02);
        a02 = fmaf(xa.z, q2.z, a02); a02 = fmaf(xa.w, q3.z, a02);
        a03 = fmaf(xa.x, q0.w, a03); a03 = fmaf(xa.y, q1.w, a03);
        a03 = fmaf(xa.z, q2.w, a03); a03 = fmaf(xa.w, q3.w, a03);
        a10 = fmaf(xb.x, q0.x, a10); a10 = fmaf(xb.y, q1.x, a10);
        a10 = fmaf(xb.z, q2.x, a10); a10 = fmaf(xb.w, q3.x, a10);
        a11 = fmaf(xb.x, q0.y, a11); a11 = fmaf(xb.y, q1.y, a11);
        a11 = fmaf(xb.z, q2.y, a11); a11 = fmaf(xb.w, q3.y, a11);
        a12 = fmaf(xb.x, q0.z, a12); a12 = fmaf(xb.y, q1.z, a12);
        a12 = fmaf(xb.z, q2.z, a12); a12 = fmaf(xb.w, q3.z, a12);
        a13 = fmaf(xb.x, q0.w, a13); a13 = fmaf(xb.y, q1.w, a13);
        a13 = fmaf(xb.z, q2.w, a13); a13 = fmaf(xb.w, q3.w, a13);
    }

    if (half == 0) {
        float4 b4 = *(const float4*)(b1 + 4 * lane);
        float4 o0 = make_float4(a00 + b4.x, a01 + b4.y, a02 + b4.z, a03 + b4.w);
        float4 o1 = make_float4(a10 + b4.x, a11 + b4.y, a12 + b4.z, a13 + b4.w);
        *(float4*)&hi_ws[(size_t)(row0 + r0 + 0) * 256 + 4 * lane] = o0;
        *(float4*)&hi_ws[(size_t)(row0 + r0 + 1) * 256 + 4 * lane] = o1;
    } else {
        const int b = row0 >> 8;
        const int m = (row0 & 255) + r0;
        float* base = hjT + (size_t)b * 65536 + (size_t)(4 * lane) * 256 + m;
        base[0 * 256 + 0] = a00; base[1 * 256 + 0] = a01;
        base[2 * 256 + 0] = a02; base[3 * 256 + 0] = a03;
        base[0 * 256 + 1] = a10; base[1 * 256 + 1] = a11;
        base[2 * 256 + 1] = a12; base[3 * 256 + 1] = a13;
    }
}

// Kernel 2: 4 n's per block (same b), 512 blocks × 256 thr (4 waves).
// Each dot phase: wave w owns a 64-wide slice of the reduction dim, lane
// owns 4 outputs via float4 global loads; partials cross-wave reduced in LDS.
__global__ __launch_bounds__(256) void k_fused(
    const float* __restrict__ x,      // [8,256,256]
    const float* __restrict__ hi_ws,  // [2048,256] (b1 folded)
    const float* __restrict__ hjT,    // [8,256,256] (b, d, m)
    const float* __restrict__ W2, const float* __restrict__ b2,
    const float* __restrict__ Wp, const float* __restrict__ bp,
    const float* __restrict__ gma, const float* __restrict__ bta,
    float* __restrict__ out)
{
    const int t = threadIdx.x;
    const int lane = t & 63, w = t >> 6;
    const int bn0 = blockIdx.x * 4;
    const int b = bn0 >> 8, n0 = bn0 & 255;

    __shared__ __align__(16) float hi_s[4][256];
    __shared__ __align__(16) float w2_s[256];
    __shared__ __align__(16) float wt_s[4][256];
    __shared__ __align__(16) float ctx_s[4][256];
    __shared__ __align__(16) float sred[4][4][256];   // [wave][n][out]
    __shared__ float part[8][4];

#pragma unroll
    for (int i = 0; i < 4; i++) hi_s[i][t] = hi_ws[(size_t)(bn0 + i) * 256 + t];
    w2_s[t] = W2[t];
    __syncthreads();

    // ---- phase 1: partial scores. wave w: d in [64w,64w+64); lane: m=4*lane..+3
    {
        const float* hjp = hjT + (size_t)b * 65536 + (size_t)(w * 64) * 256 + 4 * lane;
        float sp[4][4];
#pragma unroll
        for (int n = 0; n < 4; n++)
#pragma unroll
            for (int j = 0; j < 4; j++) sp[n][j] = 0.f;

#pragma unroll 2
        for (int dc = 0; dc < 64; dc += 4) {
            float4 h0 = *(const float4*)(hjp + (size_t)(dc + 0) * 256);
            float4 h1 = *(const float4*)(hjp + (size_t)(dc + 1) * 256);
            float4 h2 = *(const float4*)(hjp + (size_t)(dc + 2) * 256);
            float4 h3 = *(const float4*)(hjp + (size_t)(dc + 3) * 256);
            float4 wq = *(const float4*)&w2_s[w * 64 + dc];
#pragma unroll
            for (int n = 0; n < 4; n++) {
                float4 hi4 = *(const float4*)&hi_s[n][w * 64 + dc];
                sp[n][0] = fmaf(fmaxf(hi4.x + h0.x, 0.f), wq.x, sp[n][0]);
                sp[n][0] = fmaf(fmaxf(hi4.y + h1.x, 0.f), wq.y, sp[n][0]);
                sp[n][0] = fmaf(fmaxf(hi4.z + h2.x, 0.f), wq.z, sp[n][0]);
                sp[n][0] = fmaf(fmaxf(hi4.w + h3.x, 0.f), wq.w, sp[n][0]);
                sp[n][1] = fmaf(fmaxf(hi4.x + h0.y, 0.f), wq.x, sp[n][1]);
                sp[n][1] = fmaf(fmaxf(hi4.y + h1.y, 0.f), wq.y, sp[n][1]);
                sp[n][1] = fmaf(fmaxf(hi4.z + h2.y, 0.f), wq.z, sp[n][1]);
                sp[n][1] = fmaf(fmaxf(hi4.w + h3.y, 0.f), wq.w, sp[n][1]);
                sp[n][2] = fmaf(fmaxf(hi4.x + h0.z, 0.f), wq.x, sp[n][2]);
                sp[n][2] = fmaf(fmaxf(hi4.y + h1.z, 0.f), wq.y, sp[n][2]);
                sp[n][2] = fmaf(fmaxf(hi4.z + h2.z, 0.f), wq.z, sp[n][2]);
                sp[n][2] = fmaf(fmaxf(hi4.w + h3.z, 0.f), wq.w, sp[n][2]);
                sp[n][3] = fmaf(fmaxf(hi4.x + h0.w, 0.f), wq.x, sp[n][3]);
                sp[n][3] = fmaf(fmaxf(hi4.y + h1.w, 0.f), wq.y, sp[n][3]);
                sp[n][3] = fmaf(fmaxf(hi4.z + h2.w, 0.f), wq.z, sp[n][3]);
                sp[n][3] = fmaf(fmaxf(hi4.w + h3.w, 0.f), wq.w, sp[n][3]);
            }
        }
#pragma unroll
        for (int n = 0; n < 4; n++)
            *(float4*)&sred[w][n][4 * lane] =
                make_float4(sp[n][0], sp[n][1], sp[n][2], sp[n][3]);
    }
    __syncthreads();

    // ---- combine + softmax; thread t = m ----
    float b2v = b2[0];
    float s[4];
#pragma unroll
    for (int i = 0; i < 4; i++) {
        s[i] = ((sred[0][i][t] + sred[1][i][t]) +
                (sred[2][i][t] + sred[3][i][t])) + b2v;
        if (t == n0 + i) s[i] = 0.f;   // reference leaves diagonal exactly 0
    }
#pragma unroll
    for (int i = 0; i < 4; i++) {
        float m = wred_max(s[i]);
        if (lane == 0) part[i][w] = m;
    }
    __syncthreads();
    float ev[4];
#pragma unroll
    for (int i = 0; i < 4; i++) {
        float mx = fmaxf(fmaxf(part[i][0], part[i][1]),
                         fmaxf(part[i][2], part[i][3]));
        ev[i] = __expf(s[i] - mx);
        float sm = wred_sum(ev[i]);
        if (lane == 0) part[4 + i][w] = sm;
    }
    __syncthreads();
#pragma unroll
    for (int i = 0; i < 4; i++) {
        float tot = (part[4 + i][0] + part[4 + i][1]) +
                    (part[4 + i][2] + part[4 + i][3]);
        wt_s[i][t] = ev[i] / tot;
    }
    __syncthreads();

    // ---- phase 2: ctx. wave w: m in [64w,64w+64); lane: d=4*lane..+3 ----
    {
        const float* xpp = x + (size_t)b * 65536 + (size_t)(w * 64) * 256 + 4 * lane;
        float cp[4][4];
#pragma unroll
        for (int n = 0; n < 4; n++)
#pragma unroll
            for (int j = 0; j < 4; j++) cp[n][j] = 0.f;

#pragma unroll 2
        for (int mc = 0; mc < 64; mc += 4) {
            float4 x0 = *(const float4*)(xpp + (size_t)(mc + 0) * 256);
            float4 x1 = *(const float4*)(xpp + (size_t)(mc + 1) * 256);
            float4 x2 = *(const float4*)(xpp + (size_t)(mc + 2) * 256);
            float4 x3 = *(const float4*)(xpp + (size_t)(mc + 3) * 256);
#pragma unroll
            for (int n = 0; n < 4; n++) {
                float4 wt4 = *(const float4*)&wt_s[n][w * 64 + mc];
                cp[n][0] = fmaf(wt4.x, x0.x, cp[n][0]);
                cp[n][0] = fmaf(wt4.y, x1.x, cp[n][0]);
                cp[n][0] = fmaf(wt4.z, x2.x, cp[n][0]);
                cp[n][0] = fmaf(wt4.w, x3.x, cp[n][0]);
                cp[n][1] = fmaf(wt4.x, x0.y, cp[n][1]);
                cp[n][1] = fmaf(wt4.y, x1.y, cp[n][1]);
                cp[n][1] = fmaf(wt4.z, x2.y, cp[n][1]);
                cp[n][1] = fmaf(wt4.w, x3.y, cp[n][1]);
                cp[n][2] = fmaf(wt4.x, x0.z, cp[n][2]);
                cp[n][2] = fmaf(wt4.y, x1.z, cp[n][2]);
                cp[n][2] = fmaf(wt4.z, x2.z, cp[n][2]);
                cp[n][2] = fmaf(wt4.w, x3.z, cp[n][2]);
                cp[n][3] = fmaf(wt4.x, x0.w, cp[n][3]);
                cp[n][3] = fmaf(wt4.y, x1.w, cp[n][3]);
                cp[n][3] = fmaf(wt4.z, x2.w, cp[n][3]);
                cp[n][3] = fmaf(wt4.w, x3.w, cp[n][3]);
            }
        }
#pragma unroll
        for (int n = 0; n < 4; n++)
            *(float4*)&sred[w][n][4 * lane] =
                make_float4(cp[n][0], cp[n][1], cp[n][2], cp[n][3]);
    }
    __syncthreads();
#pragma unroll
    for (int i = 0; i < 4; i++)
        ctx_s[i][t] = (sred[0][i][t] + sred[1][i][t]) +
                      (sred[2][i][t] + sred[3][i][t]);
    __syncthreads();

    // ---- phase 3: proj. wave w: d in [64w,64w+64); lane: e=4*lane..+3 ----
    {
        const float* wpp = Wp + (size_t)(w * 64) * 256 + 4 * lane;
        float pq[4][4];
#pragma unroll
        for (int n = 0; n < 4; n++)
#pragma unroll
            for (int j = 0; j < 4; j++) pq[n][j] = 0.f;

#pragma unroll 2
        for (int dc = 0; dc < 64; dc += 4) {
            float4 q0 = *(const float4*)(wpp + (size_t)(dc + 0) * 256);
            float4 q1 = *(const float4*)(wpp + (size_t)(dc + 1) * 256);
            float4 q2 = *(const float4*)(wpp + (size_t)(dc + 2) * 256);
            float4 q3 = *(const float4*)(wpp + (size_t)(dc + 3) * 256);
#pragma unroll
            for (int n = 0; n < 4; n++) {
                float4 c4 = *(const float4*)&ctx_s[n][w * 64 + dc];
                pq[n][0] = fmaf(c4.x, q0.x, pq[n][0]);
                pq[n][0] = fmaf(c4.y, q1.x, pq[n][0]);
                pq[n][0] = fmaf(c4.z, q2.x, pq[n][0]);
                pq[n][0] = fmaf(c4.w, q3.x, pq[n][0]);
                pq[n][1] = fmaf(c4.x, q0.y, pq[n][1]);
                pq[n][1] = fmaf(c4.y, q1.y, pq[n][1]);
                pq[n][1] = fmaf(c4.z, q2.y, pq[n][1]);
                pq[n][1] = fmaf(c4.w, q3.y, pq[n][1]);
                pq[n][2] = fmaf(c4.x, q0.z, pq[n][2]);
                pq[n][2] = fmaf(c4.y, q1.z, pq[n][2]);
                pq[n][2] = fmaf(c4.z, q2.z, pq[n][2]);
                pq[n][2] = fmaf(c4.w, q3.z, pq[n][2]);
                pq[n][3] = fmaf(c4.x, q0.w, pq[n][3]);
                pq[n][3] = fmaf(c4.y, q1.w, pq[n][3]);
                pq[n][3] = fmaf(c4.z, q2.w, pq[n][3]);
                pq[n][3] = fmaf(c4.w, q3.w, pq[n][3]);
            }
        }
#pragma unroll
        for (int n = 0; n < 4; n++)
            *(float4*)&sred[w][n][4 * lane] =
                make_float4(pq[n][0], pq[n][1], pq[n][2], pq[n][3]);
    }
    __syncthreads();

    // ---- combine + LayerNorm + residual; thread t = e ----
    float bpv = bp[t];
    float p[4];
#pragma unroll
    for (int i = 0; i < 4; i++)
        p[i] = ((sred[0][i][t] + sred[1][i][t]) +
                (sred[2][i][t] + sred[3][i][t])) + bpv;

#pragma unroll
    for (int i = 0; i < 4; i++) {
        float su = wred_sum(p[i]);
        float sq = wred_sum(p[i] * p[i]);
        if (lane == 0) { part[i][w] = su; part[4 + i][w] = sq; }
    }
    __syncthreads();
    float gv = gma[t], bv = bta[t];
#pragma unroll
    for (int i = 0; i < 4; i++) {
        float su = (part[i][0] + part[i][1]) + (part[i][2] + part[i][3]);
        float sq = (part[4 + i][0] + part[4 + i][1]) +
                   (part[4 + i][2] + part[4 + i][3]);
        float mu = su * (1.f / 256.f);
        float var = sq * (1.f / 256.f) - mu * mu;
        float ln = (p[i] - mu) * rsqrtf(var + LN_EPS) * gv + bv;
        out[(size_t)(bn0 + i) * 256 + t] = x[(size_t)(bn0 + i) * 256 + t] + ln;
    }
}

extern "C" void kernel_launch(void* const* d_in, const int* in_sizes, int n_in,
                              void* d_out, int out_size, void* d_ws, size_t ws_size,
                              hipStream_t stream) {
    const float* x   = (const float*)d_in[0];
    const float* W1  = (const float*)d_in[1];
    const float* b1  = (const float*)d_in[2];
    const float* W2  = (const float*)d_in[3];
    const float* b2  = (const float*)d_in[4];
    const float* Wp  = (const float*)d_in[5];
    const float* bp  = (const float*)d_in[6];
    const float* gma = (const float*)d_in[7];
    const float* bta = (const float*)d_in[8];
    float* out = (float*)d_out;

    float* hi_ws = (float*)d_ws;                  // [2048,256] f32, 2 MB
    float* hjT   = hi_ws + (size_t)2048 * 256;    // [8,256,256] f32, 2 MB

    k_gemm_hij<<<512, 256, 0, stream>>>(x, W1, b1, hi_ws, hjT);
    k_fused<<<512, 256, 0, stream>>>(x, hi_ws, hjT, W2, b2, Wp, bp,
                                     gma, bta, out);
}